// Round 3
// baseline (38410.883 us; speedup 1.0000x reference)
//
#include <hip/hip_runtime.h>
#include <math.h>

#define NB 512
#define NT 256
#define BB 64
#define TT 32
#define ENCL 128
#define DD 800
#define BD (BB * TT > 0 ? BB * DD : 0)
#undef BD
#define BD (BB * DD)
#define KC 8

__device__ __forceinline__ float sigf(float x) { return 1.0f / (1.0f + __expf(-x)); }

__device__ __forceinline__ float wred(float v) {
#pragma unroll
    for (int off = 32; off > 0; off >>= 1) v += __shfl_xor(v, off);
    return v;
}

union SMEM {
    struct { float A[64 * 204]; } g;                                   // 52224 B
    struct { float cin[DD]; float h[DD]; float c[DD]; float hn[DD];
             float cw[1536]; float cb[32];
             float mw[4]; float sw[4]; float cwv[4][DD]; } ph;         // ~31.9 KB
    struct { float hv[DD]; float sc[64]; float sp[64]; } p3;
};

// -------- flag-array grid barrier: no atomic RMW, no line ping-pong --------
__device__ __forceinline__ void gbar(unsigned* flags, unsigned* rel, unsigned ep) {
    __syncthreads();
    if (threadIdx.x == 0)
        __hip_atomic_store(&flags[blockIdx.x * 32], ep, __ATOMIC_RELEASE, __HIP_MEMORY_SCOPE_AGENT);
    if (blockIdx.x == 0) {
        for (int i = threadIdx.x; i < NB; i += NT)
            while (__hip_atomic_load(&flags[i * 32], __ATOMIC_ACQUIRE, __HIP_MEMORY_SCOPE_AGENT) < ep)
                __builtin_amdgcn_s_sleep(1);
        __syncthreads();
        if (threadIdx.x == 0)
            __hip_atomic_store(rel, ep, __ATOMIC_RELEASE, __HIP_MEMORY_SCOPE_AGENT);
    } else {
        if (threadIdx.x == 0)
            while (__hip_atomic_load(rel, __ATOMIC_ACQUIRE, __HIP_MEMORY_SCOPE_AGENT) < ep)
                __builtin_amdgcn_s_sleep(2);
        __syncthreads();
    }
}

__device__ __forceinline__ void gemm_phase(int bid, int tid, const float* __restrict__ A1,
                                           const float* __restrict__ A2, const float* __restrict__ W,
                                           float* __restrict__ PB, SMEM& u) {
    if (bid >= 200) return;
    const int kc = bid & 7;
    const int dt = bid >> 3;
    const float* src = (kc < 4) ? A1 : A2;
    const int koff = (kc & 3) * 200;
    for (int i = tid; i < 64 * 200; i += NT) {
        int bb = i / 200, kk = i - bb * 200;
        u.g.A[bb * 204 + kk] = src[bb * DD + koff + kk];
    }
    __syncthreads();
    const int d16 = tid & 15;
    const int bq = tid >> 4;
    const int c0 = dt * 32 + d16;
    float acc[4][2] = {};
    const float* W0 = W + (size_t)(kc * 200) * DD;
    for (int kk = 0; kk < 200; kk += 4) {
        float wA[4], wB[4];
#pragma unroll
        for (int p = 0; p < 4; ++p) {
            wA[p] = W0[(size_t)(kk + p) * DD + c0];
            wB[p] = W0[(size_t)(kk + p) * DD + c0 + 16];
        }
#pragma unroll
        for (int rr = 0; rr < 4; ++rr) {
            const float4 a4 = *reinterpret_cast<const float4*>(&u.g.A[(bq * 4 + rr) * 204 + kk]);
            acc[rr][0] = fmaf(a4.x, wA[0], fmaf(a4.y, wA[1], fmaf(a4.z, wA[2], fmaf(a4.w, wA[3], acc[rr][0]))));
            acc[rr][1] = fmaf(a4.x, wB[0], fmaf(a4.y, wB[1], fmaf(a4.z, wB[2], fmaf(a4.w, wB[3], acc[rr][1]))));
        }
    }
#pragma unroll
    for (int rr = 0; rr < 4; ++rr) {
        int bb = bq * 4 + rr;
        PB[(size_t)(kc * BB + bb) * DD + c0] = acc[rr][0];
        PB[(size_t)(kc * BB + bb) * DD + c0 + 16] = acc[rr][1];
    }
}

__global__ __launch_bounds__(NT, 2) void persistent_kernel(
    const float* __restrict__ x, const float* __restrict__ enc,
    float* __restrict__ Hbuf, float* __restrict__ Cbuf,
    float* __restrict__ PRE, float* __restrict__ REF,
    float* __restrict__ CTX, float* __restrict__ HV1,
    float* __restrict__ PB, unsigned* flags, unsigned* rel,
    const float* __restrict__ cw0, const float* __restrict__ cb0,
    const float* __restrict__ cw1, const float* __restrict__ cb1,
    const float* __restrict__ iw0, const float* __restrict__ ib0,
    const float* __restrict__ iw1, const float* __restrict__ ib1,
    const float* __restrict__ sw0, const float* __restrict__ sb0,
    const float* __restrict__ sw1, const float* __restrict__ sb1)
{
    __shared__ SMEM u;
    const int bid = blockIdx.x;
    const int tid = threadIdx.x;
    const int lane = tid & 63;
    const int wv = tid >> 6;
    const int b = bid;                 // valid when bid < 64

    const float* cwA[2] = {cw0, cw1};
    const float* cbA[2] = {cb0, cb1};
    const float* iwA[2] = {iw0, iw1};
    const float* ibA[2] = {ib0, ib1};
    const float* swA[2] = {sw0, sw1};
    const float* sbA[2] = {sb0, sb1};

    unsigned ep = 0;

    for (int s = 0; s < TT; ++s) {
        const float* Hr = Hbuf + (size_t)(s & 1) * 2 * BD;
        float* Hw = Hbuf + (size_t)((s & 1) ^ 1) * 2 * BD;
        const float* Cr = Cbuf + (size_t)(s & 1) * 2 * BD;
        float* Cw = Cbuf + (size_t)((s & 1) ^ 1) * 2 * BD;

        for (int l = 0; l < 2; ++l) {
            const int cinx = (l == 0) ? 1 : 8;
            const int cin = cinx + 8;

            // ================= PHASE A (per-b blocks) =================
            if (bid < BB) {
                // (a) deferred REF[1][s-1] from gemm2(s-1, l=1) partials
                if (l == 0 && s >= 2) {
                    for (int i = tid; i < DD; i += NT) {
                        float sum = sb1[i];
#pragma unroll
                        for (int kc = 0; kc < KC; ++kc) sum += PB[(size_t)(kc * BB + b) * DD + i];
                        REF[((size_t)TT + (s - 1)) * BD + (size_t)b * DD + i] = tanhf(sum);
                    }
                }
                // (b) cell input
                if (l == 0) {
                    for (int i = tid; i < 100; i += NT) u.ph.cin[i] = x[(b * TT + s) * 100 + i];
                } else if (s == 0) {
                    for (int i = tid; i < DD; i += NT) u.ph.cin[i] = REF[(size_t)b * DD + i];
                } else {
                    for (int i = tid; i < DD; i += NT) {
                        float sum = sb0[i];
#pragma unroll
                        for (int kc = 0; kc < KC; ++kc) sum += PB[(size_t)(kc * BB + b) * DD + i];
                        float v = tanhf(sum);
                        u.ph.cin[i] = v;
                        REF[(size_t)s * BD + (size_t)b * DD + i] = v;   // REF[0][s]
                    }
                }
                // (c) stage h_old, c_old, conv weights
                const float* hO = Hr + (size_t)l * BD + (size_t)b * DD;
                const float* cO = Cr + (size_t)l * BD + (size_t)b * DD;
                for (int i = tid; i < DD; i += NT) { u.ph.h[i] = hO[i]; u.ph.c[i] = cO[i]; }
                const float* cwp = cwA[l];
                const int nw = 32 * cin * 3;
                for (int i = tid; i < nw; i += NT) {
                    int p = i % 3, rest = i / 3;
                    int gt = rest & 3, rest2 = rest >> 2;
                    int ic = rest2 % cin, ch = rest2 / cin;
                    u.ph.cw[i] = cwp[((gt * 8 + ch) * cin + ic) * 3 + p];
                }
                if (tid < 32) u.ph.cb[tid] = cbA[l][tid];
                __syncthreads();
                // (d) ConvLSTM cell, full row
                float* Hwr = Hw + (size_t)l * BD + (size_t)b * DD;
                float* Cwr = Cw + (size_t)l * BD + (size_t)b * DD;
                for (int i = tid; i < DD; i += NT) {
                    int col = i % 10, rch = i / 10;
                    int ch = rch & 7, r = rch >> 3;
                    float g0 = u.ph.cb[ch], g1 = u.ph.cb[8 + ch], g2 = u.ph.cb[16 + ch], g3 = u.ph.cb[24 + ch];
                    for (int ic = 0; ic < cin; ++ic) {
                        const float* zb;
                        if (ic < cinx) zb = (l == 0) ? &u.ph.cin[r * 10] : &u.ph.cin[r * 80 + ic * 10];
                        else zb = &u.ph.h[r * 80 + (ic - cinx) * 10];
                        float z0 = (col > 0) ? zb[col - 1] : 0.f;
                        float z1 = zb[col];
                        float z2 = (col < 9) ? zb[col + 1] : 0.f;
                        const float* wr = &u.ph.cw[(ch * cin + ic) * 12];
                        g0 += z0 * wr[0] + z1 * wr[1] + z2 * wr[2];
                        g1 += z0 * wr[3] + z1 * wr[4] + z2 * wr[5];
                        g2 += z0 * wr[6] + z1 * wr[7] + z2 * wr[8];
                        g3 += z0 * wr[9] + z1 * wr[10] + z2 * wr[11];
                    }
                    float c2 = sigf(g1) * u.ph.c[i] + sigf(g0) * tanhf(g2);
                    float hn = sigf(g3) * tanhf(c2);
                    u.ph.hn[i] = hn;
                    Hwr[i] = hn;
                    Cwr[i] = c2;
                }
                __syncthreads();
                // (e) one-pass online-softmax inter attention (enc read once)
                const bool has4 = (lane < 8);
                float4 q0 = *reinterpret_cast<const float4*>(&u.ph.hn[4 * lane]);
                float4 q1 = *reinterpret_cast<const float4*>(&u.ph.hn[4 * (lane + 64)]);
                float4 q2 = *reinterpret_cast<const float4*>(&u.ph.hn[4 * (lane + 128)]);
                float4 q3 = has4 ? *reinterpret_cast<const float4*>(&u.ph.hn[4 * (192 + lane)])
                                 : make_float4(0.f, 0.f, 0.f, 0.f);
                float m = -3.0e38f, ssum = 0.f;
                float4 c0 = make_float4(0, 0, 0, 0), c1 = c0, c2v = c0, c3 = c0;
                const float* ebase = enc + (size_t)b * ENCL * DD;
                for (int le = wv; le < ENCL; le += 4) {
                    const float* er = ebase + (size_t)le * DD;
                    float4 e0 = *reinterpret_cast<const float4*>(&er[4 * lane]);
                    float4 e1 = *reinterpret_cast<const float4*>(&er[4 * (lane + 64)]);
                    float4 e2 = *reinterpret_cast<const float4*>(&er[4 * (lane + 128)]);
                    float4 e3 = has4 ? *reinterpret_cast<const float4*>(&er[4 * (192 + lane)])
                                     : make_float4(0.f, 0.f, 0.f, 0.f);
                    float dot = e0.x * q0.x + e0.y * q0.y + e0.z * q0.z + e0.w * q0.w
                              + e1.x * q1.x + e1.y * q1.y + e1.z * q1.z + e1.w * q1.w
                              + e2.x * q2.x + e2.y * q2.y + e2.z * q2.z + e2.w * q2.w
                              + e3.x * q3.x + e3.y * q3.y + e3.z * q3.z + e3.w * q3.w;
                    dot = wred(dot);
                    float mn = fmaxf(m, dot);
                    float sc = __expf(m - mn);
                    float e = __expf(dot - mn);
                    ssum = ssum * sc + e;
                    c0.x = c0.x * sc + e * e0.x; c0.y = c0.y * sc + e * e0.y;
                    c0.z = c0.z * sc + e * e0.z; c0.w = c0.w * sc + e * e0.w;
                    c1.x = c1.x * sc + e * e1.x; c1.y = c1.y * sc + e * e1.y;
                    c1.z = c1.z * sc + e * e1.z; c1.w = c1.w * sc + e * e1.w;
                    c2v.x = c2v.x * sc + e * e2.x; c2v.y = c2v.y * sc + e * e2.y;
                    c2v.z = c2v.z * sc + e * e2.z; c2v.w = c2v.w * sc + e * e2.w;
                    c3.x = c3.x * sc + e * e3.x; c3.y = c3.y * sc + e * e3.y;
                    c3.z = c3.z * sc + e * e3.z; c3.w = c3.w * sc + e * e3.w;
                    m = mn;
                }
                *reinterpret_cast<float4*>(&u.ph.cwv[wv][4 * lane]) = c0;
                *reinterpret_cast<float4*>(&u.ph.cwv[wv][4 * (lane + 64)]) = c1;
                *reinterpret_cast<float4*>(&u.ph.cwv[wv][4 * (lane + 128)]) = c2v;
                if (has4) *reinterpret_cast<float4*>(&u.ph.cwv[wv][4 * (192 + lane)]) = c3;
                if (lane == 0) { u.ph.mw[wv] = m; u.ph.sw[wv] = ssum; }
                __syncthreads();
                for (int d = tid; d < DD; d += NT) {
                    float M = fmaxf(fmaxf(u.ph.mw[0], u.ph.mw[1]), fmaxf(u.ph.mw[2], u.ph.mw[3]));
                    float w0 = __expf(u.ph.mw[0] - M), w1 = __expf(u.ph.mw[1] - M);
                    float w2 = __expf(u.ph.mw[2] - M), w3 = __expf(u.ph.mw[3] - M);
                    float denom = u.ph.sw[0] * w0 + u.ph.sw[1] * w1 + u.ph.sw[2] * w2 + u.ph.sw[3] * w3;
                    float val = u.ph.cwv[0][d] * w0 + u.ph.cwv[1][d] * w1
                              + u.ph.cwv[2][d] * w2 + u.ph.cwv[3][d] * w3;
                    CTX[(size_t)b * DD + d] = val / denom;
                }
            }
            gbar(flags, rel, ++ep);

            // ================= GEMM1 =================
            gemm_phase(bid, tid, CTX, Hw + (size_t)l * BD, iwA[l], PB, u);
            gbar(flags, rel, ++ep);

            // ================= PHASE C (per-b blocks) =================
            if (bid < BB) {
                const float* ibp = ibA[l];
                for (int i = tid; i < DD; i += NT) {
                    float sum = ibp[i];
#pragma unroll
                    for (int kc = 0; kc < KC; ++kc) sum += PB[(size_t)(kc * BB + b) * DD + i];
                    u.p3.hv[i] = tanhf(sum);
                }
                __syncthreads();
                for (int i = tid; i < DD; i += NT) {
                    float v = u.p3.hv[i];
                    PRE[((size_t)l * TT + s) * BD + (size_t)b * DD + i] = v;
                    if (s == 0) REF[((size_t)l * TT) * BD + (size_t)b * DD + i] = v;
                    else HV1[(size_t)b * DD + i] = v;
                }
                if (s > 0) {
                    for (int t = wv; t < s; t += 4) {
                        const float* pr = PRE + ((size_t)l * TT + t) * BD + (size_t)b * DD;
                        float sum = 0.f;
#pragma unroll
                        for (int k = 0; k < 13; ++k) {
                            int d = lane + 64 * k;
                            if (d < DD) sum += u.p3.hv[d] * pr[d];
                        }
                        sum = wred(sum);
                        if (lane == 0) u.p3.sc[t] = sum;
                    }
                    __syncthreads();
                    if (tid < 64) {
                        float v = (tid < s) ? u.p3.sc[tid] : -3.0e38f;
                        float mm = v;
#pragma unroll
                        for (int off = 32; off > 0; off >>= 1) mm = fmaxf(mm, __shfl_xor(mm, off));
                        float e = (tid < s) ? __expf(v - mm) : 0.f;
                        float z = wred(e);
                        u.p3.sp[tid] = e / z;
                    }
                    __syncthreads();
                    for (int d = tid; d < DD; d += NT) {
                        float sum = 0.f;
                        for (int t = 0; t < s; ++t)
                            sum += u.p3.sp[t] * REF[((size_t)l * TT + t) * BD + (size_t)b * DD + d];
                        CTX[(size_t)b * DD + d] = sum;
                    }
                }
            }
            gbar(flags, rel, ++ep);

            // ================= GEMM2 (s > 0) =================
            if (s > 0) {
                gemm_phase(bid, tid, CTX, HV1, swA[l], PB, u);
                gbar(flags, rel, ++ep);
            }
        }
    }
    // final: REF[1][31] from gemm2(31, l=1) partials
    if (bid < BB) {
        for (int i = tid; i < DD; i += NT) {
            float sum = sb1[i];
#pragma unroll
            for (int kc = 0; kc < KC; ++kc) sum += PB[(size_t)(kc * BB + b) * DD + i];
            REF[((size_t)TT + 31) * BD + (size_t)b * DD + i] = tanhf(sum);
        }
    }
}

// head layer 1: [2048,800] @ [800,200] + relu
__global__ __launch_bounds__(256) void head_a(const float* __restrict__ R1,
    const float* __restrict__ w1, const float* __restrict__ b1, float* __restrict__ V1)
{
    int g = blockIdx.x * 256 + threadIdx.x;
    int row = g / 200, col = g - row * 200;
    const float* a0 = R1 + (size_t)row * DD;
    const float* a1 = a0 + (size_t)1024 * DD;
    float s0 = b1[col], s1 = s0;
    for (int k = 0; k < DD; ++k) {
        float w = w1[k * 200 + col];
        s0 = fmaf(a0[k], w, s0);
        s1 = fmaf(a1[k], w, s1);
    }
    V1[(size_t)row * 200 + col] = fmaxf(s0, 0.f);
    V1[(size_t)(row + 1024) * 200 + col] = fmaxf(s1, 0.f);
}

// head layers 2+3
__global__ __launch_bounds__(256) void head_b(const float* __restrict__ V1,
    const float* __restrict__ w2, const float* __restrict__ b2,
    const float* __restrict__ w3, const float* __restrict__ b3, float* __restrict__ out)
{
    __shared__ float v1[32][200];
    __shared__ float v2[32][50];
    int r0 = blockIdx.x * 32;
    for (int i = threadIdx.x; i < 32 * 200; i += 256) {
        int r = i / 200, c = i - r * 200;
        v1[r][c] = V1[(size_t)(r0 + r) * 200 + c];
    }
    __syncthreads();
    for (int i = threadIdx.x; i < 32 * 50; i += 256) {
        int r = i / 50, c = i - r * 50;
        float sum = b2[c];
        for (int k = 0; k < 200; ++k) sum = fmaf(v1[r][k], w2[k * 50 + c], sum);
        v2[r][c] = fmaxf(sum, 0.f);
    }
    __syncthreads();
    for (int i = threadIdx.x; i < 32 * 3; i += 256) {
        int r = i / 3, o = i - r * 3;
        float sum = b3[o];
        for (int k = 0; k < 50; ++k) sum = fmaf(v2[r][k], w3[k * 3 + o], sum);
        int row = r0 + r;
        int bb = row & 63, t = row >> 6;
        out[(bb * TT + t) * 3 + o] = sum;
    }
}

extern "C" void kernel_launch(void* const* d_in, const int* in_sizes, int n_in,
                              void* d_out, int out_size, void* d_ws, size_t ws_size,
                              hipStream_t stream)
{
    const float* x_flat = (const float*)d_in[0];
    const float* enc    = (const float*)d_in[1];
    const float* init_h = (const float*)d_in[2];
    const float* init_c = (const float*)d_in[3];
    const float* cw0 = (const float*)d_in[4];
    const float* cb0 = (const float*)d_in[5];
    const float* cw1 = (const float*)d_in[6];
    const float* cb1 = (const float*)d_in[7];
    const float* iw0 = (const float*)d_in[8];
    const float* ib0 = (const float*)d_in[9];
    const float* iw1 = (const float*)d_in[10];
    const float* ib1 = (const float*)d_in[11];
    const float* sw0 = (const float*)d_in[12];
    const float* sb0 = (const float*)d_in[13];
    const float* sw1 = (const float*)d_in[14];
    const float* sb1 = (const float*)d_in[15];
    const float* hw1 = (const float*)d_in[16];
    const float* hb1 = (const float*)d_in[17];
    const float* hw2 = (const float*)d_in[18];
    const float* hb2 = (const float*)d_in[19];
    const float* hw3 = (const float*)d_in[20];
    const float* hb3 = (const float*)d_in[21];
    float* out = (float*)d_out;

    unsigned* rel   = (unsigned*)d_ws;                       // line 0
    unsigned* flags = (unsigned*)((char*)d_ws + 256);        // 512 × 128 B
    float* base = (float*)((char*)d_ws + 256 + NB * 128);    // 65792 B offset

    float* Hbuf = base;                              // [2][2][BD]
    float* Cbuf = Hbuf + 4 * (size_t)BD;             // [2][2][BD]
    float* PRE  = Cbuf + 4 * (size_t)BD;             // [2][32][BD]
    float* REF  = PRE + 2 * (size_t)TT * BD;         // [2][32][BD]
    float* CTX  = REF + 2 * (size_t)TT * BD;         // [BD]
    float* HV1  = CTX + (size_t)BD;                  // [BD]
    float* PB   = HV1 + (size_t)BD;                  // [8][BD] (reused as V1 by head)

    hipMemsetAsync(d_ws, 0, 256 + NB * 128, stream);
    hipMemcpyAsync(Hbuf, init_h, 2 * (size_t)BD * sizeof(float), hipMemcpyDeviceToDevice, stream);
    hipMemcpyAsync(Cbuf, init_c, 2 * (size_t)BD * sizeof(float), hipMemcpyDeviceToDevice, stream);

    persistent_kernel<<<NB, NT, 0, stream>>>(
        x_flat, enc, Hbuf, Cbuf, PRE, REF, CTX, HV1, PB, flags, rel,
        cw0, cb0, cw1, cb1, iw0, ib0, iw1, ib1, sw0, sb0, sw1, sb1);

    head_a<<<800, 256, 0, stream>>>(REF + (size_t)TT * BD, hw1, hb1, PB);
    head_b<<<64, 256, 0, stream>>>(PB, hw2, hb2, hw3, hb3, out);
}

// Round 4
// 8574.903 us; speedup vs baseline: 4.4795x; 4.4795x over previous
//
#include <hip/hip_runtime.h>
#include <hip/hip_fp16.h>
#include <math.h>

#define BB 64
#define TT 32
#define ENCL 128
#define DD 800
#define TPB 1024

typedef _Float16 h2 __attribute__((ext_vector_type(2)));

__device__ __forceinline__ h2 u2h(unsigned u) { union { unsigned u; h2 h; } c; c.u = u; return c.h; }
__device__ __forceinline__ unsigned pack2(float a, float b) {
    union { unsigned u; h2 h; } c; c.h[0] = (_Float16)a; c.h[1] = (_Float16)b; return c.u;
}
__device__ __forceinline__ float sigf(float x) { return 1.f / (1.f + __expf(-x)); }
__device__ __forceinline__ float wred(float v) {
#pragma unroll
    for (int o = 32; o > 0; o >>= 1) v += __shfl_xor(v, o);
    return v;
}
__device__ __forceinline__ float wmax(float v) {
#pragma unroll
    for (int o = 32; o > 0; o >>= 1) v = fmaxf(v, __shfl_xor(v, o));
    return v;
}

#if __has_builtin(__builtin_amdgcn_fdot2)
__device__ __forceinline__ float FDOT2(h2 a, h2 b, float c) { return __builtin_amdgcn_fdot2(a, b, c, false); }
#else
__device__ __forceinline__ float FDOT2(h2 a, h2 b, float c) {
    return c + (float)a[0] * (float)b[0] + (float)a[1] * (float)b[1];
}
#endif

// ---- prep: W[1600][800] f32 -> [400][800] uint2 (4 consecutive k as half) ----
__global__ __launch_bounds__(256) void pack_w4(const float* __restrict__ W, uint2* __restrict__ out) {
    int i = blockIdx.x * 256 + threadIdx.x;          // 320000
    if (i >= 400 * 800) return;
    int c = i % 800, kq = i / 800;
    const float* src = W + (size_t)(4 * kq) * 800 + c;
    uint2 r;
    r.x = pack2(src[0], src[800]);
    r.y = pack2(src[1600], src[2400]);
    out[i] = r;
}

// ---- prep: f32 pairs -> half2 words ----
__global__ __launch_bounds__(256) void pack_pairs(const float* __restrict__ in, unsigned* __restrict__ out, int n2) {
    int i = blockIdx.x * 256 + threadIdx.x;
    if (i < n2) out[i] = pack2(in[2 * i], in[2 * i + 1]);
}

// ---- prep: head w1 [800][200] f32 -> [400][200] half2 (k-pairs) ----
__global__ __launch_bounds__(256) void pack_w1(const float* __restrict__ w1, unsigned* __restrict__ out) {
    int i = blockIdx.x * 256 + threadIdx.x;          // 80000
    if (i >= 400 * 200) return;
    int c = i % 200, kp = i / 200;
    out[i] = pack2(w1[(2 * kp) * 200 + c], w1[(2 * kp + 1) * 200 + c]);
}

// =================== the whole decoder: one block per batch row ===================
__global__ __launch_bounds__(TPB, 1) void decoder_kernel(
    const float* __restrict__ x, const __half* __restrict__ ench,
    const uint2* __restrict__ iwp0, const uint2* __restrict__ iwp1,
    const uint2* __restrict__ swp0, const uint2* __restrict__ swp1,
    const float* __restrict__ ib0, const float* __restrict__ ib1,
    const float* __restrict__ sb0, const float* __restrict__ sb1,
    const float* __restrict__ cw0, const float* __restrict__ cb0,
    const float* __restrict__ cw1, const float* __restrict__ cb1,
    const float* __restrict__ init_h, const float* __restrict__ init_c,
    __half* __restrict__ PREh, __half* __restrict__ REFh,
    const unsigned* __restrict__ w1p, const float* __restrict__ hb1,
    const float* __restrict__ hw2, const float* __restrict__ hb2,
    const float* __restrict__ hw3, const float* __restrict__ hb3,
    float* __restrict__ out)
{
    __shared__ float cwS[2][1536];
    __shared__ float cbS[2][32];
    __shared__ float HC[2][2][DD];     // [layer][h=0/c=1][d]
    __shared__ float cin[DD];
    __shared__ float hn[DD];
    __shared__ float hv[DD];
    __shared__ unsigned xh[DD];        // GEMV input: 1600 halfs as 800 half2 words
    __shared__ float sc[128];
    __shared__ float pw[128];

    const int b = blockIdx.x;
    const int tid = threadIdx.x;
    const int lane = tid & 63;
    const int wv = tid >> 6;           // 16 waves

    const uint2* iwp[2] = {iwp0, iwp1};
    const uint2* swp[2] = {swp0, swp1};
    const float* ib[2] = {ib0, ib1};
    const float* sb[2] = {sb0, sb1};
    const float* cwA[2] = {cw0, cw1};
    const float* cbA[2] = {cb0, cb1};

    // ---- one-time staging: conv weights (both layers) + initial state ----
    for (int l2 = 0; l2 < 2; ++l2) {
        const int cin_l = l2 ? 16 : 9;
        const int nw = 32 * cin_l * 3;
        for (int i = tid; i < nw; i += TPB) {
            int p = i % 3, rest = i / 3;
            int gt = rest & 3, rest2 = rest >> 2;
            int ic = rest2 % cin_l, ch = rest2 / cin_l;
            cwS[l2][(ch * cin_l + ic) * 12 + gt * 3 + p] = cwA[l2][((gt * 8 + ch) * cin_l + ic) * 3 + p];
        }
        for (int i = tid; i < 32; i += TPB) cbS[l2][i] = cbA[l2][i];
        for (int i = tid; i < DD; i += TPB) {
            HC[l2][0][i] = init_h[((size_t)l2 * BB + b) * DD + i];
            HC[l2][1][i] = init_c[((size_t)l2 * BB + b) * DD + i];
        }
    }
    __syncthreads();

    const unsigned* encu = (const unsigned*)ench;

    for (int s = 0; s < TT; ++s) {
        for (int l = 0; l < 2; ++l) {
            const int cinx = (l == 0) ? 1 : 8;
            const int cin_l = cinx + 8;
            // ---- A: cell input (l==1: cin already holds layer-0 output) ----
            if (l == 0) {
                for (int i = tid; i < 100; i += TPB) cin[i] = x[((size_t)b * TT + s) * 100 + i];
            }
            __syncthreads();
            // ---- B: ConvLSTM cell ----
            if (tid < DD) {
                const int col = tid % 10, rch = tid / 10;
                const int ch = rch & 7, r = rch >> 3;
                float g0 = cbS[l][ch], g1 = cbS[l][8 + ch], g2 = cbS[l][16 + ch], g3 = cbS[l][24 + ch];
                for (int ic = 0; ic < cin_l; ++ic) {
                    const float* zb = (ic < cinx)
                        ? ((l == 0) ? &cin[r * 10] : &cin[r * 80 + ic * 10])
                        : &HC[l][0][r * 80 + (ic - cinx) * 10];
                    float z0 = (col > 0) ? zb[col - 1] : 0.f;
                    float z1 = zb[col];
                    float z2 = (col < 9) ? zb[col + 1] : 0.f;
                    const float* wr = &cwS[l][(ch * cin_l + ic) * 12];
                    g0 += z0 * wr[0] + z1 * wr[1] + z2 * wr[2];
                    g1 += z0 * wr[3] + z1 * wr[4] + z2 * wr[5];
                    g2 += z0 * wr[6] + z1 * wr[7] + z2 * wr[8];
                    g3 += z0 * wr[9] + z1 * wr[10] + z2 * wr[11];
                }
                float c2 = sigf(g1) * HC[l][1][tid] + sigf(g0) * tanhf(g2);
                float hnv = sigf(g3) * tanhf(c2);
                hn[tid] = hnv;
                HC[l][1][tid] = c2;                     // c: in-place safe (per-thread)
            }
            __syncthreads();
            if (tid < DD) HC[l][0][tid] = hn[tid];      // h: after all neighbor reads
            if (tid < 400) xh[400 + tid] = pack2(hn[2 * tid], hn[2 * tid + 1]);
            __syncthreads();
            // ---- C: inter-attention scores (16 waves x 8 enc rows) ----
            for (int r8 = 0; r8 < 8; ++r8) {
                const int le = wv * 8 + r8;
                const unsigned* erow = encu + ((size_t)b * ENCL + le) * 400;
                float sum = 0.f;
                for (int d2 = lane; d2 < 400; d2 += 64)
                    sum = FDOT2(u2h(erow[d2]), u2h(xh[400 + d2]), sum);
                sum = wred(sum);
                if (lane == 0) sc[le] = sum;
            }
            __syncthreads();
            // ---- D: softmax over 128 (wave 0) ----
            if (wv == 0) {
                float v0 = sc[lane], v1 = sc[64 + lane];
                float m = wmax(fmaxf(v0, v1));
                float e0 = __expf(v0 - m), e1 = __expf(v1 - m);
                float S = wred(e0 + e1);
                float inv = 1.f / S;
                pw[lane] = e0 * inv;
                pw[64 + lane] = e1 * inv;
            }
            __syncthreads();
            // ---- E: ctx = sum_le pw[le] * enc[b][le][:] ----
            if (tid < DD) {
                const __half* eh = ench + (size_t)b * ENCL * DD + tid;
                float acc = 0.f;
                for (int le = 0; le < ENCL; ++le) acc += pw[le] * (float)eh[(size_t)le * DD];
                hv[tid] = acc;                          // scratch
            }
            __syncthreads();
            if (tid < 400) xh[tid] = pack2(hv[2 * tid], hv[2 * tid + 1]);
            __syncthreads();
            // ---- F: GEMV1: cat(ctx, h) @ iw + ib -> tanh -> hv ----
            if (tid < DD) {
                float acc = ib[l][tid];
                const uint2* wp = iwp[l] + tid;
                const uint2* xv = (const uint2*)xh;
#pragma unroll 4
                for (int kq = 0; kq < 400; ++kq) {
                    uint2 w4 = wp[(size_t)kq * 800];
                    uint2 x4 = xv[kq];
                    acc = FDOT2(u2h(w4.x), u2h(x4.x), acc);
                    acc = FDOT2(u2h(w4.y), u2h(x4.y), acc);
                }
                float hvv = tanhf(acc);
                hv[tid] = hvv;
                PREh[(((size_t)l * BB + b) * TT + s) * DD + tid] = (__half)hvv;
            }
            __syncthreads();
            if (tid < 400) xh[400 + tid] = pack2(hv[2 * tid], hv[2 * tid + 1]);
            __syncthreads();
            if (s == 0) {
                if (tid < DD) {
                    float v = hv[tid];
                    REFh[(((size_t)l * BB + b) * TT + 0) * DD + tid] = (__half)v;
                    if (l == 0) cin[tid] = v;
                }
                __syncthreads();
            } else {
                // ---- G: self-attn scores over t' < s ----
                for (int tp = wv; tp < s; tp += 16) {
                    const unsigned* pr = (const unsigned*)PREh + (((size_t)l * BB + b) * TT + tp) * 400;
                    float sum = 0.f;
                    for (int d2 = lane; d2 < 400; d2 += 64)
                        sum = FDOT2(u2h(pr[d2]), u2h(xh[400 + d2]), sum);
                    sum = wred(sum);
                    if (lane == 0) sc[tp] = sum;
                }
                __syncthreads();
                // ---- H: softmax over s entries (wave 0) ----
                if (wv == 0) {
                    float v = (lane < s) ? sc[lane] : -3.0e38f;
                    float m = wmax(v);
                    float e = (lane < s) ? __expf(v - m) : 0.f;
                    float S = wred(e);
                    if (lane < 32) pw[lane] = e / S;
                }
                __syncthreads();
                // ---- I: ctx2 = sum_t' pw[t'] * ref[t'] ----
                if (tid < DD) {
                    const __half* rr = REFh + (((size_t)l * BB + b) * TT) * DD + tid;
                    float acc = 0.f;
                    for (int tp = 0; tp < s; ++tp) acc += pw[tp] * (float)rr[(size_t)tp * DD];
                    cin[tid] = acc;                     // scratch (cell done with cin)
                }
                __syncthreads();
                if (tid < 400) xh[tid] = pack2(cin[2 * tid], cin[2 * tid + 1]);
                __syncthreads();
                // ---- J: GEMV2: cat(ctx2, hv) @ sw + sb -> tanh -> layer out ----
                if (tid < DD) {
                    float acc = sb[l][tid];
                    const uint2* wp = swp[l] + tid;
                    const uint2* xv = (const uint2*)xh;
#pragma unroll 4
                    for (int kq = 0; kq < 400; ++kq) {
                        uint2 w4 = wp[(size_t)kq * 800];
                        uint2 x4 = xv[kq];
                        acc = FDOT2(u2h(w4.x), u2h(x4.x), acc);
                        acc = FDOT2(u2h(w4.y), u2h(x4.y), acc);
                    }
                    float lv = tanhf(acc);
                    REFh[(((size_t)l * BB + b) * TT + s) * DD + tid] = (__half)lv;
                    if (l == 0) cin[tid] = lv;          // next layer's input
                }
                __syncthreads();
            }
        }
    }

    // =================== head MLP for this block's 32 rows ===================
    unsigned* r8 = reinterpret_cast<unsigned*>(&HC[0][0][0]);   // 8 x 400 u32
    float* v1s = &cwS[0][0];                                     // 1600 f32
    float* v2s = &cwS[0][0] + 1600;                              // 400 f32
    const unsigned* refu = (const unsigned*)REFh + (((size_t)BB + b) * TT) * 400;  // l=1 rows
    for (int g = 0; g < 4; ++g) {
        for (int i = tid; i < 8 * 400; i += TPB)
            r8[i] = refu[(size_t)(g * 8 + i / 400) * 400 + (i % 400)];
        __syncthreads();
        for (int o = tid; o < 1600; o += TPB) {         // [8 rows][200 cols]
            int tr = o / 200, c = o % 200;
            float acc = hb1[c];
            const unsigned* rrow = &r8[tr * 400];
#pragma unroll 4
            for (int kp = 0; kp < 400; ++kp)
                acc = FDOT2(u2h(w1p[kp * 200 + c]), u2h(rrow[kp]), acc);
            v1s[o] = fmaxf(acc, 0.f);
        }
        __syncthreads();
        for (int o = tid; o < 400; o += TPB) {          // [8][50]
            int tr = o / 50, c = o % 50;
            float acc = hb2[c];
            for (int k = 0; k < 200; ++k) acc = fmaf(v1s[tr * 200 + k], hw2[k * 50 + c], acc);
            v2s[o] = fmaxf(acc, 0.f);
        }
        __syncthreads();
        for (int o = tid; o < 24; o += TPB) {           // [8][3]
            int tr = o / 3, oo = o % 3;
            float acc = hb3[oo];
            for (int k = 0; k < 50; ++k) acc = fmaf(v2s[tr * 50 + k], hw3[k * 3 + oo], acc);
            out[((size_t)b * TT + g * 8 + tr) * 3 + oo] = acc;
        }
        __syncthreads();
    }
}

extern "C" void kernel_launch(void* const* d_in, const int* in_sizes, int n_in,
                              void* d_out, int out_size, void* d_ws, size_t ws_size,
                              hipStream_t stream)
{
    const float* x_flat = (const float*)d_in[0];
    const float* enc    = (const float*)d_in[1];
    const float* init_h = (const float*)d_in[2];
    const float* init_c = (const float*)d_in[3];
    const float* cw0 = (const float*)d_in[4];
    const float* cb0 = (const float*)d_in[5];
    const float* cw1 = (const float*)d_in[6];
    const float* cb1 = (const float*)d_in[7];
    const float* iw0 = (const float*)d_in[8];
    const float* ib0 = (const float*)d_in[9];
    const float* iw1 = (const float*)d_in[10];
    const float* ib1 = (const float*)d_in[11];
    const float* sw0 = (const float*)d_in[12];
    const float* sb0 = (const float*)d_in[13];
    const float* sw1 = (const float*)d_in[14];
    const float* sb1 = (const float*)d_in[15];
    const float* hw1 = (const float*)d_in[16];
    const float* hb1 = (const float*)d_in[17];
    const float* hw2 = (const float*)d_in[18];
    const float* hb2 = (const float*)d_in[19];
    const float* hw3 = (const float*)d_in[20];
    const float* hb3 = (const float*)d_in[21];
    float* out = (float*)d_out;

    char* p = (char*)d_ws;
    uint2* iwp0 = (uint2*)p; p += (size_t)400 * 800 * 8;   // 2.56 MB each
    uint2* iwp1 = (uint2*)p; p += (size_t)400 * 800 * 8;
    uint2* swp0 = (uint2*)p; p += (size_t)400 * 800 * 8;
    uint2* swp1 = (uint2*)p; p += (size_t)400 * 800 * 8;
    __half* ench = (__half*)p; p += (size_t)BB * ENCL * DD * 2;        // 13.1 MB
    unsigned* w1p = (unsigned*)p; p += (size_t)400 * 200 * 4;          // 320 KB
    __half* PREh = (__half*)p; p += (size_t)2 * BB * TT * DD * 2;      // 6.55 MB
    __half* REFh = (__half*)p; p += (size_t)2 * BB * TT * DD * 2;      // 6.55 MB

    pack_w4<<<1250, 256, 0, stream>>>(iw0, iwp0);
    pack_w4<<<1250, 256, 0, stream>>>(iw1, iwp1);
    pack_w4<<<1250, 256, 0, stream>>>(sw0, swp0);
    pack_w4<<<1250, 256, 0, stream>>>(sw1, swp1);
    pack_pairs<<<12800, 256, 0, stream>>>(enc, (unsigned*)ench, BB * ENCL * DD / 2);
    pack_w1<<<313, 256, 0, stream>>>(hw1, w1p);

    decoder_kernel<<<BB, TPB, 0, stream>>>(
        x_flat, ench, iwp0, iwp1, swp0, swp1, ib0, ib1, sb0, sb1,
        cw0, cb0, cw1, cb1, init_h, init_c, PREh, REFh,
        w1p, hb1, hw2, hb2, hw3, hb3, out);
}